// Round 1
// baseline (722.675 us; speedup 1.0000x reference)
//
#include <hip/hip_runtime.h>

// 2-layer LSTM (H=2, I=1) + dense sigmoid head.
// One thread per batch element; full T-recurrence in registers.

__device__ __forceinline__ float fast_sigmoid(float x) {
    // 1/(1 + 2^(-x*log2(e)))  -> v_exp_f32 + v_rcp_f32, saturates correctly
    float e = __builtin_amdgcn_exp2f(-1.4426950408889634f * x);
    return __builtin_amdgcn_rcpf(1.0f + e);
}

__device__ __forceinline__ float fast_tanh(float x) {
    // tanh(x) = 1 - 2/(1 + 2^(2x*log2(e)))
    float e = __builtin_amdgcn_exp2f(2.8853900817779268f * x);
    return 1.0f - 2.0f * __builtin_amdgcn_rcpf(1.0f + e);
}

__global__ __launch_bounds__(64, 1)
void lstm2_kernel(const float* __restrict__ x,
                  const float* __restrict__ Wih0, const float* __restrict__ Whh0,
                  const float* __restrict__ bih0, const float* __restrict__ bhh0,
                  const float* __restrict__ Wih1, const float* __restrict__ Whh1,
                  const float* __restrict__ bih1, const float* __restrict__ bhh1,
                  const float* __restrict__ Wd,   const float* __restrict__ bd,
                  float* __restrict__ out, int B, int T)
{
    const int b = blockIdx.x * 64 + threadIdx.x;
    if (b >= B) return;

    // Gate order (PyTorch): i (rows 0-1), f (2-3), g (4-5), o (6-7)
    float wih0[8], bs0[8], whh0a[8], whh0b[8];
    float wih1a[8], wih1b[8], whh1a[8], whh1b[8], bs1[8];
#pragma unroll
    for (int j = 0; j < 8; ++j) {
        wih0[j]  = Wih0[j];                  // [8][1]
        bs0[j]   = bih0[j] + bhh0[j];
        whh0a[j] = Whh0[2*j];  whh0b[j] = Whh0[2*j+1];   // [8][2]
        wih1a[j] = Wih1[2*j];  wih1b[j] = Wih1[2*j+1];   // [8][2]
        whh1a[j] = Whh1[2*j];  whh1b[j] = Whh1[2*j+1];   // [8][2]
        bs1[j]   = bih1[j] + bhh1[j];
    }
    const float wd0 = Wd[0], wd1 = Wd[1], bdv = bd[0];

    const float4* xb = reinterpret_cast<const float4*>(x + (size_t)b * (size_t)T);

    float h00=0.f, h01=0.f, c00=0.f, c01=0.f;   // layer 0 state
    float h10=0.f, h11=0.f, c10=0.f, c11=0.f;   // layer 1 state

    const int nT4 = T >> 2;
    for (int t4 = 0; t4 < nT4; ++t4) {
        const float4 xv = xb[t4];
        const float xs[4] = {xv.x, xv.y, xv.z, xv.w};
#pragma unroll
        for (int k = 0; k < 4; ++k) {
            const float xt = xs[k];

            // ---- layer 0 ----
            float g[8];
#pragma unroll
            for (int j = 0; j < 8; ++j)
                g[j] = fmaf(whh0b[j], h01, fmaf(whh0a[j], h00, fmaf(wih0[j], xt, bs0[j])));
            const float i0 = fast_sigmoid(g[0]), i1 = fast_sigmoid(g[1]);
            const float f0 = fast_sigmoid(g[2]), f1 = fast_sigmoid(g[3]);
            const float u0 = fast_tanh(g[4]),    u1 = fast_tanh(g[5]);
            const float o0 = fast_sigmoid(g[6]), o1 = fast_sigmoid(g[7]);
            c00 = fmaf(f0, c00, i0*u0);
            c01 = fmaf(f1, c01, i1*u1);
            h00 = o0 * fast_tanh(c00);
            h01 = o1 * fast_tanh(c01);

            // ---- layer 1 ----
            float q[8];
#pragma unroll
            for (int j = 0; j < 8; ++j)
                q[j] = fmaf(whh1b[j], h11, fmaf(whh1a[j], h10,
                        fmaf(wih1b[j], h01, fmaf(wih1a[j], h00, bs1[j]))));
            const float I0 = fast_sigmoid(q[0]), I1 = fast_sigmoid(q[1]);
            const float F0 = fast_sigmoid(q[2]), F1 = fast_sigmoid(q[3]);
            const float U0 = fast_tanh(q[4]),    U1 = fast_tanh(q[5]);
            const float O0 = fast_sigmoid(q[6]), O1 = fast_sigmoid(q[7]);
            c10 = fmaf(F0, c10, I0*U0);
            c11 = fmaf(F1, c11, I1*U1);
            h10 = O0 * fast_tanh(c10);
            h11 = O1 * fast_tanh(c11);
        }
    }

    out[b] = fast_sigmoid(fmaf(wd1, h11, fmaf(wd0, h10, bdv)));
}

extern "C" void kernel_launch(void* const* d_in, const int* in_sizes, int n_in,
                              void* d_out, int out_size, void* d_ws, size_t ws_size,
                              hipStream_t stream)
{
    const float* x    = (const float*)d_in[0];
    const float* Wih0 = (const float*)d_in[1];
    const float* Whh0 = (const float*)d_in[2];
    const float* bih0 = (const float*)d_in[3];
    const float* bhh0 = (const float*)d_in[4];
    const float* Wih1 = (const float*)d_in[5];
    const float* Whh1 = (const float*)d_in[6];
    const float* bih1 = (const float*)d_in[7];
    const float* bhh1 = (const float*)d_in[8];
    const float* Wd   = (const float*)d_in[9];
    const float* bd   = (const float*)d_in[10];
    float* out = (float*)d_out;

    const int B = out_size;            // 16384
    const int T = in_sizes[0] / B;     // 2048

    dim3 block(64), grid((B + 63) / 64);
    lstm2_kernel<<<grid, block, 0, stream>>>(x, Wih0, Whh0, bih0, bhh0,
                                             Wih1, Whh1, bih1, bhh1, Wd, bd,
                                             out, B, T);
}

// Round 2
// 247.708 us; speedup vs baseline: 2.9174x; 2.9174x over previous
//
#include <hip/hip_runtime.h>

// 2-layer LSTM (H=2, I=1) + dense sigmoid head.
// 4 lanes per batch chain: lane sub = layer*2 + component.
// Layer 1 runs one timestep behind layer 0 (software pipeline);
// intra-quad scalar exchange via DPP quad_perm (no LDS, no divergence).

__device__ __forceinline__ float fast_sigmoid(float x) {
    float e = __builtin_amdgcn_exp2f(-1.4426950408889634f * x);
    return __builtin_amdgcn_rcpf(1.0f + e);
}
__device__ __forceinline__ float fast_tanh(float x) {
    float e = __builtin_amdgcn_exp2f(2.8853900817779268f * x);
    return 1.0f - 2.0f * __builtin_amdgcn_rcpf(1.0f + e);
}

// quad_perm DPP move: CTRL = p0 | p1<<2 | p2<<4 | p3<<6
template<int CTRL>
__device__ __forceinline__ float dpp_f(float v) {
    return __int_as_float(__builtin_amdgcn_update_dpp(
        0, __float_as_int(v), CTRL, 0xF, 0xF, true));
}
// 0xB1 = [1,0,3,2]  swap within pairs (partner component, same layer)
// 0x44 = [0,1,0,1]  lanes 2,3 receive lanes 0,1 (layer0 -> layer1 transfer)

__global__ __launch_bounds__(256, 1)
void lstm2_quad_kernel(const float* __restrict__ x,
                       const float* __restrict__ Wih0, const float* __restrict__ Whh0,
                       const float* __restrict__ bih0, const float* __restrict__ bhh0,
                       const float* __restrict__ Wih1, const float* __restrict__ Whh1,
                       const float* __restrict__ bih1, const float* __restrict__ bhh1,
                       const float* __restrict__ Wd,   const float* __restrict__ bd,
                       float* __restrict__ out, int B, int T)
{
    const int tid   = blockIdx.x * 256 + threadIdx.x;
    const int chain = tid >> 2;
    if (chain >= B) return;
    const int  sub   = tid & 3;        // 0:L0c0 1:L0c1 2:L1c0 3:L1c1
    const int  comp  = sub & 1;
    const bool is_l1 = (sub & 2) != 0;

    // Per-lane gate coefficients. Gate order g=0..3 -> i,f,u,o; row j = 2g+comp.
    // gate = wA*in_a + wB*in_b + wHo*h_own + wHp*h_partner + bs
    // layer0: in_a = x_t (wB=0). layer1: in_a/in_b are h0 comps in per-lane order.
    float wA[4], wB[4], wHo[4], wHp[4], bs[4];
#pragma unroll
    for (int g = 0; g < 4; ++g) {
        const int j = 2 * g + comp;
        if (!is_l1) {
            wA[g]  = Wih0[j];
            wB[g]  = 0.0f;
            wHo[g] = Whh0[2 * j + comp];
            wHp[g] = Whh0[2 * j + 1 - comp];
            bs[g]  = bih0[j] + bhh0[j];
        } else {
            wA[g]  = Wih1[2 * j + comp];
            wB[g]  = Wih1[2 * j + 1 - comp];
            wHo[g] = Whh1[2 * j + comp];
            wHp[g] = Whh1[2 * j + 1 - comp];
            bs[g]  = bih1[j] + bhh1[j];
        }
    }

    float h = 0.f, c = 0.f;            // own (layer, comp) state
    float hp = 0.f;                    // partner comp, same layer
    float ina = 0.f, inb = 0.f;        // layer0 h outputs routed to layer1 lanes

    const float4* xb = reinterpret_cast<const float4*>(x + (size_t)chain * (size_t)T);

    auto step = [&](float xt) {
        const float a0 = is_l1 ? ina : xt;
        float g0 = fmaf(wA[0], a0, fmaf(wB[0], inb, fmaf(wHo[0], h, fmaf(wHp[0], hp, bs[0]))));
        float g1 = fmaf(wA[1], a0, fmaf(wB[1], inb, fmaf(wHo[1], h, fmaf(wHp[1], hp, bs[1]))));
        float g2 = fmaf(wA[2], a0, fmaf(wB[2], inb, fmaf(wHo[2], h, fmaf(wHp[2], hp, bs[2]))));
        float g3 = fmaf(wA[3], a0, fmaf(wB[3], inb, fmaf(wHo[3], h, fmaf(wHp[3], hp, bs[3]))));
        const float iv = fast_sigmoid(g0);
        const float fv = fast_sigmoid(g1);
        const float uv = fast_tanh(g2);
        const float ov = fast_sigmoid(g3);
        c = fmaf(fv, c, iv * uv);
        h = ov * fast_tanh(c);
        hp  = dpp_f<0xB1>(h);     // partner h (same layer)
        ina = dpp_f<0x44>(h);     // lane2<-lane0 (h0_0), lane3<-lane1 (h0_1)
        inb = dpp_f<0xB1>(ina);   // the other h0 component
    };

    // Peeled t=0: layer0 does real work; layer1 result is bogus -> reset it.
    float4 v = xb[0];
    step(v.x);
    if (is_l1) { h = 0.f; c = 0.f; }
    hp  = dpp_f<0xB1>(h);
    ina = dpp_f<0x44>(h);
    inb = dpp_f<0xB1>(ina);

    step(v.y); step(v.z); step(v.w);

    const int nT4 = T >> 2;
    for (int t4 = 1; t4 < nT4; ++t4) {
        v = xb[t4];
        step(v.x); step(v.y); step(v.z); step(v.w);
    }

    // Final skewed iteration: layer1 consumes h0(T-1); layer0 input = 0 (unused).
    step(0.f);

    // Lane sub==2 holds h1_0; its hp (set in final step) = h1_1.
    if (sub == 2) {
        out[chain] = fast_sigmoid(fmaf(Wd[1], hp, fmaf(Wd[0], h, bd[0])));
    }
}

extern "C" void kernel_launch(void* const* d_in, const int* in_sizes, int n_in,
                              void* d_out, int out_size, void* d_ws, size_t ws_size,
                              hipStream_t stream)
{
    const float* x    = (const float*)d_in[0];
    const float* Wih0 = (const float*)d_in[1];
    const float* Whh0 = (const float*)d_in[2];
    const float* bih0 = (const float*)d_in[3];
    const float* bhh0 = (const float*)d_in[4];
    const float* Wih1 = (const float*)d_in[5];
    const float* Whh1 = (const float*)d_in[6];
    const float* bih1 = (const float*)d_in[7];
    const float* bhh1 = (const float*)d_in[8];
    const float* Wd   = (const float*)d_in[9];
    const float* bd   = (const float*)d_in[10];
    float* out = (float*)d_out;

    const int B = out_size;            // 16384
    const int T = in_sizes[0] / B;     // 2048

    const int threads = B * 4;         // 4 lanes per chain
    dim3 block(256), grid((threads + 255) / 256);
    lstm2_quad_kernel<<<grid, block, 0, stream>>>(x, Wih0, Whh0, bih0, bhh0,
                                                  Wih1, Whh1, bih1, bhh1, Wd, bd,
                                                  out, B, T);
}

// Round 3
// 227.446 us; speedup vs baseline: 3.1774x; 1.0891x over previous
//
#include <hip/hip_runtime.h>

// 2-layer LSTM (H=2, I=1) + dense sigmoid head.
// 4 lanes per chain (sub = layer*2 + comp), DPP quad_perm exchange,
// batched-rcp activations (7 trans/step vs 10), pk_fma gate dots,
// double-buffered x prefetch.

typedef float f2 __attribute__((ext_vector_type(2)));

__device__ __forceinline__ float fast_sigmoid(float x) {
    float e = __builtin_amdgcn_exp2f(-1.4426950408889634f * x);
    return __builtin_amdgcn_rcpf(1.0f + e);
}

template<int CTRL>
__device__ __forceinline__ float dpp_f(float v) {
    return __int_as_float(__builtin_amdgcn_update_dpp(
        0, __float_as_int(v), CTRL, 0xF, 0xF, true));
}
// 0xB1 = [1,0,3,2] partner comp, same layer
// 0x44 = [0,1,0,1] lanes 2,3 <- lanes 0,1 (h0 own-order)
// 0x11 = [1,0,1,0] lanes 2,3 <- lanes 1,0 (h0 cross-order)

__global__ __launch_bounds__(256, 1)
void lstm2_quad_kernel(const float* __restrict__ x,
                       const float* __restrict__ Wih0, const float* __restrict__ Whh0,
                       const float* __restrict__ bih0, const float* __restrict__ bhh0,
                       const float* __restrict__ Wih1, const float* __restrict__ Whh1,
                       const float* __restrict__ bih1, const float* __restrict__ bhh1,
                       const float* __restrict__ Wd,   const float* __restrict__ bd,
                       float* __restrict__ out, int B, int T)
{
    const int tid   = blockIdx.x * 256 + threadIdx.x;
    const int chain = tid >> 2;
    if (chain >= B) return;
    const int  sub   = tid & 3;        // 0:L0c0 1:L0c1 2:L1c0 3:L1c1
    const int  comp  = sub & 1;
    const bool is_l1 = (sub & 2) != 0;

    // Per-lane gate coefficients; gate g=0..3 -> i,f,u,o; weight row j = 2g+comp.
    float wa[4], wb[4], who[4], whp[4], bsv[4];
#pragma unroll
    for (int g = 0; g < 4; ++g) {
        const int j = 2 * g + comp;
        if (!is_l1) {
            wa[g]  = Wih0[j];
            wb[g]  = 0.0f;
            who[g] = Whh0[2 * j + comp];
            whp[g] = Whh0[2 * j + 1 - comp];
            bsv[g] = bih0[j] + bhh0[j];
        } else {
            wa[g]  = Wih1[2 * j + comp];
            wb[g]  = Wih1[2 * j + 1 - comp];
            who[g] = Whh1[2 * j + comp];
            whp[g] = Whh1[2 * j + 1 - comp];
            bsv[g] = bih1[j] + bhh1[j];
        }
    }
    const f2 wA_lo = {wa[0], wa[1]},  wA_hi = {wa[2], wa[3]};
    const f2 wB_lo = {wb[0], wb[1]},  wB_hi = {wb[2], wb[3]};
    const f2 wO_lo = {who[0], who[1]}, wO_hi = {who[2], who[3]};
    const f2 wP_lo = {whp[0], whp[1]}, wP_hi = {whp[2], whp[3]};
    const f2 bs_lo = {bsv[0], bsv[1]}, bs_hi = {bsv[2], bsv[3]};

    const float K1 = 1.4426950408889634f;
    const f2 sc_lo = {-K1, -K1};         // i,f: sigmoid -> exp2(-K g)
    const f2 sc_hi = {2.f * K1, -K1};    // u: tanh -> exp2(+2K g); o: sigmoid

    float h = 0.f, c = 0.f, hp = 0.f, ina = 0.f, inb = 0.f;

    auto step = [&](float xt) {
        const float a0 = is_l1 ? ina : xt;
        const f2 a02 = {a0, a0}, ib2 = {inb, inb}, h2 = {h, h}, hp2 = {hp, hp};
        f2 gLo = __builtin_elementwise_fma(wA_lo, a02,
                 __builtin_elementwise_fma(wB_lo, ib2, bs_lo));
        gLo    = __builtin_elementwise_fma(wO_lo, h2,
                 __builtin_elementwise_fma(wP_lo, hp2, gLo));
        f2 gHi = __builtin_elementwise_fma(wA_hi, a02,
                 __builtin_elementwise_fma(wB_hi, ib2, bs_hi));
        gHi    = __builtin_elementwise_fma(wO_hi, h2,
                 __builtin_elementwise_fma(wP_hi, hp2, gHi));
        const f2 mLo = gLo * sc_lo, mHi = gHi * sc_hi;
        const float e0 = __builtin_amdgcn_exp2f(mLo.x);
        const float e1 = __builtin_amdgcn_exp2f(mLo.y);
        const float e2 = __builtin_amdgcn_exp2f(mHi.x);
        const float e3 = __builtin_amdgcn_exp2f(mHi.y);
        const float A0 = 1.f + e0, A1 = 1.f + e1, A2 = 1.f + e2, A3 = 1.f + e3;
        const float Q01 = A0 * A1, Q23 = A2 * A3;
        const float r   = __builtin_amdgcn_rcpf(Q01 * Q23);
        const float r01 = Q23 * r;   // 1/(A0*A1)
        const float r23 = Q01 * r;   // 1/(A2*A3)
        const float iv  = A1 * r01;  // sigmoid(g0) = 1/A0
        const float fv  = A0 * r01;  // sigmoid(g1) = 1/A1
        const float tu  = A3 * r23;  // 1/A2
        const float ov  = A2 * r23;  // sigmoid(g3) = 1/A3
        const float uv  = fmaf(-2.f, tu, 1.f);   // tanh(g2)
        c = fmaf(fv, c, iv * uv);
        const float ec = __builtin_amdgcn_exp2f((2.f * K1) * c);
        const float tc = fmaf(-2.f, __builtin_amdgcn_rcpf(1.f + ec), 1.f);
        h = ov * tc;
        hp  = dpp_f<0xB1>(h);
        ina = dpp_f<0x44>(h);
        inb = dpp_f<0x11>(h);
    };

    const float4* xb = reinterpret_cast<const float4*>(x + (size_t)chain * (size_t)T);
    const int nT4 = T >> 2;

    float4 cur = xb[0];
    float4 nxt = xb[1];

    // Peeled t=0: layer1 result is bogus -> reset, re-propagate h.
    step(cur.x);
    if (is_l1) { h = 0.f; c = 0.f; }
    hp  = dpp_f<0xB1>(h);
    ina = dpp_f<0x44>(h);
    inb = dpp_f<0x11>(h);
    step(cur.y); step(cur.z); step(cur.w);

    for (int t4 = 1; t4 < nT4 - 1; ++t4) {
        cur = nxt;
        nxt = xb[t4 + 1];
        step(cur.x); step(cur.y); step(cur.z); step(cur.w);
    }
    cur = nxt;
    step(cur.x); step(cur.y); step(cur.z); step(cur.w);

    // Final skewed iteration: layer1 consumes h0(T-1).
    step(0.f);

    // Lane sub==2: h = h1_0, hp = h1_1.
    if (sub == 2) {
        out[chain] = fast_sigmoid(fmaf(Wd[1], hp, fmaf(Wd[0], h, bd[0])));
    }
}

extern "C" void kernel_launch(void* const* d_in, const int* in_sizes, int n_in,
                              void* d_out, int out_size, void* d_ws, size_t ws_size,
                              hipStream_t stream)
{
    const float* x    = (const float*)d_in[0];
    const float* Wih0 = (const float*)d_in[1];
    const float* Whh0 = (const float*)d_in[2];
    const float* bih0 = (const float*)d_in[3];
    const float* bhh0 = (const float*)d_in[4];
    const float* Wih1 = (const float*)d_in[5];
    const float* Whh1 = (const float*)d_in[6];
    const float* bih1 = (const float*)d_in[7];
    const float* bhh1 = (const float*)d_in[8];
    const float* Wd   = (const float*)d_in[9];
    const float* bd   = (const float*)d_in[10];
    float* out = (float*)d_out;

    const int B = out_size;            // 16384
    const int T = in_sizes[0] / B;     // 2048

    const int threads = B * 4;
    dim3 block(256), grid((threads + 255) / 256);
    lstm2_quad_kernel<<<grid, block, 0, stream>>>(x, Wih0, Whh0, bih0, bhh0,
                                                  Wih1, Whh1, bih1, bhh1, Wd, bd,
                                                  out, B, T);
}

// Round 4
// 206.048 us; speedup vs baseline: 3.5073x; 1.1038x over previous
//
#include <hip/hip_runtime.h>

// 2-layer LSTM (H=2, I=1) + dense sigmoid head.
// 4 lanes per chain (sub = layer*2 + comp), DPP quad_perm exchange.
// Gate weights prescaled by exp2 constants; c kept in scaled domain;
// product-form c/h update so all reconstruction hides under the rcp.

typedef float f2 __attribute__((ext_vector_type(2)));

__device__ __forceinline__ float fast_sigmoid(float x) {
    float e = __builtin_amdgcn_exp2f(-1.4426950408889634f * x);
    return __builtin_amdgcn_rcpf(1.0f + e);
}

template<int CTRL>
__device__ __forceinline__ float dpp_f(float v) {
    return __int_as_float(__builtin_amdgcn_update_dpp(
        0, __float_as_int(v), CTRL, 0xF, 0xF, true));
}
// 0xB1 = [1,0,3,2] partner comp, same layer
// 0x44 = [0,1,0,1] lanes 2,3 <- lanes 0,1 (h0 own-order)
// 0x11 = [1,0,1,0] lanes 2,3 <- lanes 1,0 (h0 cross-order)

__global__ __launch_bounds__(256, 1)
void lstm2_quad_kernel(const float* __restrict__ x,
                       const float* __restrict__ Wih0, const float* __restrict__ Whh0,
                       const float* __restrict__ bih0, const float* __restrict__ bhh0,
                       const float* __restrict__ Wih1, const float* __restrict__ Whh1,
                       const float* __restrict__ bih1, const float* __restrict__ bhh1,
                       const float* __restrict__ Wd,   const float* __restrict__ bd,
                       float* __restrict__ out, int B, int T)
{
    const int tid   = blockIdx.x * 256 + threadIdx.x;
    const int chain = tid >> 2;
    if (chain >= B) return;
    const int  sub   = tid & 3;        // 0:L0c0 1:L0c1 2:L1c0 3:L1c1
    const int  comp  = sub & 1;
    const bool is_l1 = (sub & 2) != 0;

    const float K1 = 1.4426950408889634f;
    const float K2 = 2.8853900817779268f;   // 2*log2(e)

    // Per-lane gate coefficients, PRESCALED: gates i,f,o by -K1 (sigmoid via
    // exp2(-K*g)), gate u by +K2 (tanh via exp2(2K*g)). g index: 0=i,1=f,2=u,3=o.
    float wa[4], wb[4], who[4], whp[4], bsv[4];
#pragma unroll
    for (int g = 0; g < 4; ++g) {
        const int j = 2 * g + comp;
        const float s = (g == 2) ? K2 : -K1;
        if (!is_l1) {
            wa[g]  = s * Wih0[j];
            wb[g]  = 0.0f;
            who[g] = s * Whh0[2 * j + comp];
            whp[g] = s * Whh0[2 * j + 1 - comp];
            bsv[g] = s * (bih0[j] + bhh0[j]);
        } else {
            wa[g]  = s * Wih1[2 * j + comp];
            wb[g]  = s * Wih1[2 * j + 1 - comp];
            who[g] = s * Whh1[2 * j + comp];
            whp[g] = s * Whh1[2 * j + 1 - comp];
            bsv[g] = s * (bih1[j] + bhh1[j]);
        }
    }
    const f2 wA_lo = {wa[0], wa[1]},  wA_hi = {wa[2], wa[3]};
    const f2 wB_lo = {wb[0], wb[1]},  wB_hi = {wb[2], wb[3]};
    const f2 wO_lo = {who[0], who[1]}, wO_hi = {who[2], who[3]};
    const f2 wP_lo = {whp[0], whp[1]}, wP_hi = {whp[2], whp[3]};
    const f2 bs_lo = {bsv[0], bsv[1]}, bs_hi = {bsv[2], bsv[3]};

    float h = 0.f, C = 0.f;            // C = K2 * c  (scaled cell state)
    float hp = 0.f, ina = 0.f, inb = 0.f;

    auto step = [&](float xt) {
        const float a0 = is_l1 ? ina : xt;
        const f2 a02 = {a0, a0}, ib2 = {inb, inb}, h2 = {h, h}, hp2 = {hp, hp};
        // h enters at the LAST fma (shortest path from recurrence).
        f2 gLo = __builtin_elementwise_fma(wB_lo, ib2,
                 __builtin_elementwise_fma(wA_lo, a02, bs_lo));
        gLo    = __builtin_elementwise_fma(wO_lo, h2,
                 __builtin_elementwise_fma(wP_lo, hp2, gLo));
        f2 gHi = __builtin_elementwise_fma(wB_hi, ib2,
                 __builtin_elementwise_fma(wA_hi, a02, bs_hi));
        gHi    = __builtin_elementwise_fma(wO_hi, h2,
                 __builtin_elementwise_fma(wP_hi, hp2, gHi));
        const float e0 = __builtin_amdgcn_exp2f(gLo.x);
        const float e1 = __builtin_amdgcn_exp2f(gLo.y);
        const float e2 = __builtin_amdgcn_exp2f(gHi.x);
        const float e3 = __builtin_amdgcn_exp2f(gHi.y);
        const float A0 = 1.f + e0, A1 = 1.f + e1, A2 = 1.f + e2, A3 = 1.f + e3;
        // sigmoid(i)=1/A0, sigmoid(f)=1/A1, tanh(u)=(A2-2)/A2, sigmoid(o)=1/A3
        const float Q01 = A0 * A1, Q23 = A2 * A3, A13 = A1 * A3;
        const float r   = __builtin_amdgcn_rcpf(Q01 * Q23);
        const float t2  = fmaf(K2, A2, -2.f * K2);   // K2*(A2-2)
        const float M   = t2 * A13;                  // K2*(A2-2)*A1*A3
        const float N   = A0 * Q23;                  // A0*A2*A3
        const float S   = fmaf(N, C, M);             // (in shadow of rcp)
        const float OVp = Q01 * A2;
        C = r * S;                                   // C_new = K2*c_new
        const float ov = OVp * r;                    // sigmoid(o)
        const float ec = __builtin_amdgcn_exp2f(C);  // exp(2*c_new)
        const float R  = __builtin_amdgcn_rcpf(1.f + ec);
        const float th = fmaf(-2.f, R, 1.f);         // tanh(c_new)
        h = ov * th;
        hp  = dpp_f<0xB1>(h);
        ina = dpp_f<0x44>(h);
        inb = dpp_f<0x11>(h);
    };

    const float4* xb = reinterpret_cast<const float4*>(x + (size_t)chain * (size_t)T);
    const int nT4 = T >> 2;

    float4 cur = xb[0];
    float4 nxt = xb[1];

    // Peeled t=0: layer1 result is bogus -> reset, re-propagate h.
    step(cur.x);
    if (is_l1) { h = 0.f; C = 0.f; }
    hp  = dpp_f<0xB1>(h);
    ina = dpp_f<0x44>(h);
    inb = dpp_f<0x11>(h);
    step(cur.y); step(cur.z); step(cur.w);

    for (int t4 = 1; t4 < nT4 - 1; ++t4) {
        cur = nxt;
        nxt = xb[t4 + 1];
        step(cur.x); step(cur.y); step(cur.z); step(cur.w);
    }
    cur = nxt;
    step(cur.x); step(cur.y); step(cur.z); step(cur.w);

    // Final skewed iteration: layer1 consumes h0(T-1).
    step(0.f);

    // Lane sub==2: h = h1_0, hp = h1_1.
    if (sub == 2) {
        out[chain] = fast_sigmoid(fmaf(Wd[1], hp, fmaf(Wd[0], h, bd[0])));
    }
}

extern "C" void kernel_launch(void* const* d_in, const int* in_sizes, int n_in,
                              void* d_out, int out_size, void* d_ws, size_t ws_size,
                              hipStream_t stream)
{
    const float* x    = (const float*)d_in[0];
    const float* Wih0 = (const float*)d_in[1];
    const float* Whh0 = (const float*)d_in[2];
    const float* bih0 = (const float*)d_in[3];
    const float* bhh0 = (const float*)d_in[4];
    const float* Wih1 = (const float*)d_in[5];
    const float* Whh1 = (const float*)d_in[6];
    const float* bih1 = (const float*)d_in[7];
    const float* bhh1 = (const float*)d_in[8];
    const float* Wd   = (const float*)d_in[9];
    const float* bd   = (const float*)d_in[10];
    float* out = (float*)d_out;

    const int B = out_size;            // 16384
    const int T = in_sizes[0] / B;     // 2048

    const int threads = B * 4;
    dim3 block(256), grid((threads + 255) / 256);
    lstm2_quad_kernel<<<grid, block, 0, stream>>>(x, Wih0, Whh0, bih0, bhh0,
                                                  Wih1, Whh1, bih1, bhh1, Wd, bd,
                                                  out, B, T);
}